// Round 10
// baseline (326.968 us; speedup 1.0000x reference)
//
#include <hip/hip_runtime.h>
#include <stdint.h>

// Problem constants
#define SEQ   2048
#define NNODE 16384      // B*S = 8*2048

typedef short  short8  __attribute__((ext_vector_type(8)));   // 8 bf16 (4 VGPR)
typedef float  float4v __attribute__((ext_vector_type(4)));
typedef unsigned short u16;
typedef unsigned short u16x8 __attribute__((ext_vector_type(8)));
typedef short  short4v __attribute__((ext_vector_type(4)));

__device__ __forceinline__ float b2f(u16 u) {
    union { unsigned int i; float f; } x; x.i = ((unsigned int)u) << 16; return x.f;
}
__device__ __forceinline__ u16 f2b(float f) {
    union { float f; unsigned int i; } x; x.f = f;
    unsigned int u = x.i;
    unsigned int r = (u + 0x7fffu + ((u >> 16) & 1u)) >> 16;  // RNE
    return (u16)r;
}

__device__ __forceinline__ void gld16(const void* g, void* l) {
    __builtin_amdgcn_global_load_lds(
        (const __attribute__((address_space(1))) void*)g,
        (__attribute__((address_space(3))) void*)l, 16, 0, 0);
}

struct GemmP {
    const void*  A[2];
    const u16*   B[2];
    const float* bias[2];
    u16*         out[2];
};

// ---------------------------------------------------------------------------
// G1: FINE-PHASE 256x128-tile GEMM, fp32 A staged to LDS via gld16 (no reg
// round-trip, no ds_writes), bf16 convert AFTER lgkmcnt(0) via proven f2b.
//   512 thr = 8 waves (4M x 2N), per-wave 64x64, acc[4][4]. BK=32.
//   LDS ring-3: 3 x (A 32KB fp32 + B 8KB bf16) = 120 KB, 1 blk/CU.
//   Per K-tile (one phase): { 8 ds_read_b128 A-fp32 + 4 ds_read_b128 B |
//     stage tile T+2 (4 A-gld16 + 1 B-gld16) | s_waitcnt vmcnt(5) |
//     s_barrier | lgkmcnt(0) | setprio(1) cvt+16 MFMA setprio(0) |
//     s_barrier }.
//   vmcnt(5) exact: queue = [T+1's 5 | T+2's 5] -> drains T+1, T+2 stays in
//   flight. NEVER 0 in the loop. Ring-3 slot safety: slot (T+2)%3 was last
//   read in tile T-1, whose reads completed before T-1's end barrier.
//   Swizzle (involution, stage-source + read): A 16B-chunk ^= row&7
//   (8 chunks/row), B chunk ^= row&3 (4 chunks/row).
//   Why this variant: coarse-fused G1 = 70-80us (r1/r8/r9); fine+reg-cvt =
//   107us (cvt+ds_write in lockstep phase, r7); fine-bf16+cvt-pass = ~104us
//   net (r5). fp32-in-LDS moves the cvt after lgkm0 where it interleaves
//   with MFMA issue, and keeps staging pure-DMA.
// ---------------------------------------------------------------------------
template <int ACT>
__global__ __launch_bounds__(512, 2) void gemmf1_k(GemmP p, int M, int N, int K) {
    __shared__ __align__(16) u16 smem[61440];   // 120 KB

    const int z = blockIdx.z;
    const float* __restrict__ A32  = (const float*)p.A[z];
    const u16*   __restrict__ Bg   = p.B[z];
    const float* __restrict__ bias = p.bias[z];

    // XCD-chunked bijective swizzle (256 blocks/side). The 4 nt-blocks of
    // one mt land on the same XCD (flat differs by 8) -> A-panel L2 reuse.
    const int nblk = gridDim.x;            // 256
    const int cpx  = nblk >> 3;
    const int flat = blockIdx.x;
    const int swz  = (flat & 7) * cpx + (flat >> 3);
    const int mt   = (swz >> 2) * 256;     // nbn = 4
    const int nt   = (swz & 3) * 128;

    const int tid = threadIdx.x;
    const int l   = tid & 63;
    const int w   = tid >> 6;
    const int wm  = w >> 1;           // 0..3  (64-row group)
    const int wn  = w & 1;            // 0..1  (64-col group)
    const int lr  = l & 15;
    const int lk  = l >> 4;
    (void)M;

    float4v acc[4][4] = {};

    float* const Af0 = (float*)smem;       // A ring: 0, 8192, 16384 floats
    u16*   const Bs0 = smem + 49152;       // B ring: +0, +4096, +8192 u16

    // A staging: 2048 chunk-slots, 4 gld16/thread; f=it*512+tid, row=f>>3,
    // slot=f&7, global chunk = slot^(row&7). Dest linear (lane x 16B).
    auto stageA = [&](int k0, float* dst) {
#pragma unroll
        for (int it = 0; it < 4; ++it) {
            const int f = it * 512 + tid;
            const int row = f >> 3;
            const int gc = (f & 7) ^ (row & 7);
            gld16(A32 + (size_t)(mt + row) * K + k0 + gc * 4, dst + (size_t)f * 4);
        }
    };
    // B staging: 512 chunk-slots, 1 gld16/thread; row=tid>>2, slot=tid&3.
    auto stageB = [&](int k0, u16* dst) {
        const int row = tid >> 2;
        const int gc  = (tid & 3) ^ (row & 3);
        gld16(Bg + (size_t)(nt + row) * K + k0 + gc * 8, dst + (size_t)tid * 8);
    };

    const int NT = K >> 5;   // 32 K-tiles of 32

    // ---- prologue: stage tiles 0,1 (10 loads), drain tile 0 ----
    stageA(0, Af0);          stageB(0, Bs0);
    stageA(32, Af0 + 8192);  stageB(32, Bs0 + 4096);
    asm volatile("s_waitcnt vmcnt(5)" ::: "memory");
    __builtin_amdgcn_s_barrier();

    // ---- main loop ----
    int sc = 0;
    for (int T = 0; T < NT; ++T) {
        const int sc2 = (sc >= 1) ? sc - 1 : 2;        // (T+2)%3
        const float* Ac = Af0 + sc * 8192;
        const u16*   Bc = Bs0 + sc * 4096;
        float* A2 = Af0 + sc2 * 8192;
        u16*   B2 = Bs0 + sc2 * 4096;
        const int k2 = (T + 2 < NT) ? (T + 2) << 5 : 0;  // clamp keeps vmcnt

        // reads: A fragments as 2x float4 (chunks 2lk, 2lk^1), B as b128
        float4v va[4], vb[4];
        short8 bq[4];
#pragma unroll
        for (int mi = 0; mi < 4; ++mi) {
            const int row = wm * 64 + mi * 16 + lr;
            const float* ab = Ac + (size_t)row * 32;
            const int s0 = (2 * lk) ^ (row & 7);
            va[mi] = *(const float4v*)(ab + s0 * 4);
            vb[mi] = *(const float4v*)(ab + (s0 ^ 1) * 4);
        }
#pragma unroll
        for (int ni = 0; ni < 4; ++ni) {
            const int row = wn * 64 + ni * 16 + lr;
            bq[ni] = *(const short8*)(Bc + (size_t)row * 32 +
                                      ((lk ^ (row & 3)) << 3));
        }
        stageA(k2, A2);
        stageB(k2, B2);
        asm volatile("s_waitcnt vmcnt(5)" ::: "memory");
        __builtin_amdgcn_s_barrier();
        asm volatile("s_waitcnt lgkmcnt(0)" ::: "memory");
        __builtin_amdgcn_s_setprio(1);
        short8 af[4];
#pragma unroll
        for (int mi = 0; mi < 4; ++mi) {
            short8 r;
            r[0] = (short)f2b(va[mi][0]); r[1] = (short)f2b(va[mi][1]);
            r[2] = (short)f2b(va[mi][2]); r[3] = (short)f2b(va[mi][3]);
            r[4] = (short)f2b(vb[mi][0]); r[5] = (short)f2b(vb[mi][1]);
            r[6] = (short)f2b(vb[mi][2]); r[7] = (short)f2b(vb[mi][3]);
            af[mi] = r;
        }
#pragma unroll
        for (int mi = 0; mi < 4; ++mi)
#pragma unroll
            for (int ni = 0; ni < 4; ++ni)
                acc[mi][ni] = __builtin_amdgcn_mfma_f32_16x16x32_bf16(
                    af[mi], bq[ni], acc[mi][ni], 0, 0, 0);
        __builtin_amdgcn_s_setprio(0);
        __builtin_amdgcn_s_barrier();
        sc = (sc == 2) ? 0 : sc + 1;
    }

    __syncthreads();   // full drain: tail gld16 DMA must land before LDS reuse

    // ---- epilogue: C/D layout col=lane&15, row=(lane>>4)*4+reg ----
    const int er0 = lk * 4;
    float bvv[4];
#pragma unroll
    for (int ni = 0; ni < 4; ++ni) bvv[ni] = bias[nt + wn * 64 + ni * 16 + lr];
#pragma unroll
    for (int mi = 0; mi < 4; ++mi)
#pragma unroll
        for (int ni = 0; ni < 4; ++ni) {
            const int lc = wn * 64 + ni * 16 + lr;
#pragma unroll
            for (int r = 0; r < 4; ++r) {
                float v = acc[mi][ni][r] + bvv[ni];
                if (ACT) v = v > 0.f ? v : 0.01f * v;
                smem[(size_t)(wm * 64 + mi * 16 + er0 + r) * 136 + lc] = f2b(v);
            }
        }
    __syncthreads();
#pragma unroll
    for (int it = 0; it < 8; ++it) {
        const int id  = it * 512 + tid;
        const int row = id >> 4, colc = id & 15;
        u16x8 vv = *(const u16x8*)(smem + (size_t)row * 136 + colc * 8);
        *(u16x8*)(p.out[z] + (size_t)(mt + row) * N + nt + colc * 8) = vv;
    }
}

// ---------------------------------------------------------------------------
// FINE-PHASE 256x128-tile bf16 GEMM (r5/r8 skeleton). Used for G2/G3.
// ---------------------------------------------------------------------------
#define FPHASE(ASL, BSL, KH, STAGE, DO_VM)                                    \
    {                                                                         \
        short8 af[4], bq[4];                                                  \
        _Pragma("unroll") for (int mi = 0; mi < 4; ++mi)                      \
            af[mi] = *(const short8*)((ASL) +                                 \
                (size_t)(wm * 64 + mi * 16 + lr) * 64 +                       \
                (((KH) * 4 + lk) ^ (lr & 7)) * 8);                            \
        _Pragma("unroll") for (int ni = 0; ni < 4; ++ni)                      \
            bq[ni] = *(const short8*)((BSL) +                                 \
                (size_t)(wn * 64 + ni * 16 + lr) * 64 +                       \
                (((KH) * 4 + lk) ^ (lr & 7)) * 8);                            \
        STAGE;                                                                \
        if (DO_VM) asm volatile("s_waitcnt vmcnt(6)" ::: "memory");           \
        __builtin_amdgcn_s_barrier();                                         \
        asm volatile("s_waitcnt lgkmcnt(0)" ::: "memory");                    \
        __builtin_amdgcn_s_setprio(1);                                        \
        _Pragma("unroll") for (int mi = 0; mi < 4; ++mi)                      \
            _Pragma("unroll") for (int ni = 0; ni < 4; ++ni)                  \
                acc[mi][ni] = __builtin_amdgcn_mfma_f32_16x16x32_bf16(        \
                    af[mi], bq[ni], acc[mi][ni], 0, 0, 0);                    \
        __builtin_amdgcn_s_setprio(0);                                        \
        __builtin_amdgcn_s_barrier();                                         \
    }

template <int ACT>
__global__ __launch_bounds__(512, 2) void gemmt_k(GemmP p, int M, int N, int K) {
    __shared__ __align__(16) u16 smem[73728];   // 144 KB

    const int z = blockIdx.z;
    const u16*   __restrict__ Ag   = (const u16*)p.A[z];
    const u16*   __restrict__ Bg   = p.B[z];
    const float* __restrict__ bias = p.bias[z];

    const int nblk = gridDim.x;
    const int cpx  = nblk >> 3;
    const int flat = blockIdx.x;
    const int swz  = (flat & 7) * cpx + (flat >> 3);
    const int nbn  = N >> 7;
    const int mt   = (swz / nbn) * 256;
    const int nt   = (swz % nbn) * 128;

    const int tid = threadIdx.x;
    const int l   = tid & 63;
    const int w   = tid >> 6;
    const int wm  = w >> 1;
    const int wn  = w & 1;
    const int lr  = l & 15;
    const int lk  = l >> 4;
    (void)M;

    float4v acc[4][4] = {};

    const int srow   = tid >> 3;
    const int gchunk = (tid & 7) ^ (srow & 7);

    u16* const As0 = smem;            // A ring: 0, 16384, 32768 (u16)
    u16* const Bs0 = smem + 49152;    // B ring: +0, +8192, +16384

    auto stageA = [&](int k0, u16* dst) {
#pragma unroll
        for (int i = 0; i < 4; ++i)
            gld16(Ag + (size_t)(mt + srow + 64 * i) * K + k0 + gchunk * 8,
                  dst + (size_t)(tid + 512 * i) * 8);
    };
    auto stageB = [&](int k0, u16* dst) {
#pragma unroll
        for (int i = 0; i < 2; ++i)
            gld16(Bg + (size_t)(nt + srow + 64 * i) * K + k0 + gchunk * 8,
                  dst + (size_t)(tid + 512 * i) * 8);
    };

    const int NT = K >> 6;

    stageA(0, As0);          stageB(0, Bs0);
    stageA(64, As0 + 16384); stageB(64, Bs0 + 8192);
    asm volatile("s_waitcnt vmcnt(6)" ::: "memory");
    __builtin_amdgcn_s_barrier();

    int sc = 0;
    for (int T = 0; T < NT; ++T) {
        const int sc2 = (sc >= 1) ? sc - 1 : 2;
        u16* Ac = As0 + sc  * 16384;  u16* Bc = Bs0 + sc  * 8192;
        u16* A2 = As0 + sc2 * 16384;  u16* B2 = Bs0 + sc2 * 8192;
        const int k2 = (T + 2 < NT) ? (T + 2) << 6 : 0;
        FPHASE(Ac, Bc, 0, stageA(k2, A2), 0)
        FPHASE(Ac, Bc, 1, stageB(k2, B2), 1)
        sc = (sc == 2) ? 0 : sc + 1;
    }

    __syncthreads();

    const int er0 = lk * 4;
    float bvv[4];
#pragma unroll
    for (int ni = 0; ni < 4; ++ni) bvv[ni] = bias[nt + wn * 64 + ni * 16 + lr];
#pragma unroll
    for (int mi = 0; mi < 4; ++mi)
#pragma unroll
        for (int ni = 0; ni < 4; ++ni) {
            const int lc = wn * 64 + ni * 16 + lr;
#pragma unroll
            for (int r = 0; r < 4; ++r) {
                float v = acc[mi][ni][r] + bvv[ni];
                if (ACT) v = v > 0.f ? v : 0.01f * v;
                smem[(size_t)(wm * 64 + mi * 16 + er0 + r) * 136 + lc] = f2b(v);
            }
        }
    __syncthreads();
#pragma unroll
    for (int it = 0; it < 8; ++it) {
        const int id  = it * 512 + tid;
        const int row = id >> 4, colc = id & 15;
        u16x8 vv = *(const u16x8*)(smem + (size_t)row * 136 + colc * 8);
        *(u16x8*)(p.out[z] + (size_t)(mt + row) * N + nt + colc * 8) = vv;
    }
}

// ---------------------------------------------------------------------------
// LDS-tiled weight transpose+convert: fp32 [K,N] -> bf16 [N,K], 64x64 tiles
// ---------------------------------------------------------------------------
struct TP { const float* src[6]; u16* dst[6]; int K[6]; int N[6]; };

__global__ __launch_bounds__(256) void transpose_k(TP t) {
    __shared__ float tile[64][65];
    const int m = blockIdx.y;
    const int K = t.K[m], N = t.N[m];
    const int tn = N >> 6;
    const int ntiles = (K >> 6) * tn;
    const int bid = blockIdx.x;
    if (bid >= ntiles) return;
    const int k0 = (bid / tn) * 64, n0 = (bid % tn) * 64;
    const int tid = threadIdx.x;
#pragma unroll
    for (int pass = 0; pass < 4; ++pass) {
        int kk = pass * 16 + (tid >> 4);
        int nn = (tid & 15) * 4;
        float4v v = *(const float4v*)(t.src[m] + (size_t)(k0 + kk) * N + n0 + nn);
        tile[kk][nn + 0] = v[0]; tile[kk][nn + 1] = v[1];
        tile[kk][nn + 2] = v[2]; tile[kk][nn + 3] = v[3];
    }
    __syncthreads();
    const int n = tid >> 2, kc = (tid & 3) * 16;
    u16x8 a, b;
#pragma unroll
    for (int j = 0; j < 8; ++j) {
        a[j] = f2b(tile[kc + j][n]);
        b[j] = f2b(tile[kc + 8 + j][n]);
    }
    u16* d = t.dst[m] + (size_t)(n0 + n) * K + k0 + kc;
    *(u16x8*)d = a;
    *(u16x8*)(d + 8) = b;
}

// EW[t][c] = sum_e emb[t][e] * W_edge[e][c]  (64x256 fp32, 4 partials)
__global__ void ew_k(const float* emb, const float* W_edge, float* EW) {
    const int t = blockIdx.x, c = threadIdx.x;
    float p0 = 0.f, p1 = 0.f, p2 = 0.f, p3 = 0.f;
    for (int e = 0; e < 64; e += 4) {
        p0 += emb[t * 64 + e + 0] * W_edge[(e + 0) * 256 + c];
        p1 += emb[t * 64 + e + 1] * W_edge[(e + 1) * 256 + c];
        p2 += emb[t * 64 + e + 2] * W_edge[(e + 2) * 256 + c];
        p3 += emb[t * 64 + e + 3] * W_edge[(e + 3) * 256 + c];
    }
    EW[t * 256 + c] = (p0 + p1) + (p2 + p3);
}

// bcat = [b_msg | b_self]  (512 fp32)
__global__ void bias_cat_k(const float* bmsg, const float* bself, float* bcat) {
    const int tid = threadIdx.x;
    bcat[tid]       = bmsg[tid];
    bcat[256 + tid] = bself[tid];
}

// ---------------------------------------------------------------------------
// Epilogue: out_i = xself[i] + valid_i*(xmsg[head_i] + EW[type_i]);
//           L2-normalize; accumulate per-batch sum (later /2048).
// alpha == valid exactly (dst=arange -> singleton segments -> softmax = 1).
// ---------------------------------------------------------------------------
struct EpiP {
    const u16* xcat[2];
    const int* den[2]; const int* spa[2]; const int* arc[2];
    const int* wty[2]; const int* wma[2];
    const float* EW; float* racc;
};

__global__ __launch_bounds__(256) void epi_k(EpiP p) {
    __shared__ float part[4][256];
    const int bx    = blockIdx.x;
    const int side  = bx >> 9;           // 512 blocks per side
    const int local = bx & 511;
    const int base  = local * 32;        // 32 nodes/block (same batch: 32|2048)
    const int b     = base >> 11;
    const int tid   = threadIdx.x;
    const int w = tid >> 6, l = tid & 63;

    const u16* __restrict__ xcat = p.xcat[side];

    float4v acc = {};
    for (int j = 0; j < 8; ++j) {
        const int i     = base + w * 8 + j;
        const int valid = p.den[side][i] * p.spa[side][i];
        const int srcn  = p.arc[side][i] + (i >> 11) * SEQ;
        const int t     = p.wty[side][i] * p.wma[side][i];
        short4v xs = *(const short4v*)(xcat + (size_t)i * 512 + 256 + l * 4);
        short4v xm = *(const short4v*)(xcat + (size_t)srcn * 512 + l * 4);
        float4v ew = *(const float4v*)(p.EW + (size_t)t * 256 + l * 4);
        const float vm = valid ? 1.f : 0.f;
        float4v v;
        v[0] = b2f((u16)xs[0]) + vm * (b2f((u16)xm[0]) + ew[0]);
        v[1] = b2f((u16)xs[1]) + vm * (b2f((u16)xm[1]) + ew[1]);
        v[2] = b2f((u16)xs[2]) + vm * (b2f((u16)xm[2]) + ew[2]);
        v[3] = b2f((u16)xs[3]) + vm * (b2f((u16)xm[3]) + ew[3]);
        float ss = v[0]*v[0] + v[1]*v[1] + v[2]*v[2] + v[3]*v[3];
        for (int m = 32; m >= 1; m >>= 1) ss += __shfl_xor(ss, m, 64);
        const float rn = 1.f / fmaxf(sqrtf(ss), 1e-12f);
        acc[0] += v[0] * rn; acc[1] += v[1] * rn;
        acc[2] += v[2] * rn; acc[3] += v[3] * rn;
    }
    part[w][l * 4 + 0] = acc[0];
    part[w][l * 4 + 1] = acc[1];
    part[w][l * 4 + 2] = acc[2];
    part[w][l * 4 + 3] = acc[3];
    __syncthreads();
    const float s = part[0][tid] + part[1][tid] + part[2][tid] + part[3][tid];
    atomicAdd(p.racc + ((size_t)side * 8 + b) * 256 + tid, s);
}

// out[side,b,c] = (racc[side,b,:]/2048) @ Wf[:,c] + bf[c]   (fp32 out)
__global__ void fin_k(const float* racc, const float* Wf, const float* bfv,
                      float* out) {
    __shared__ float r[256];
    const int bid = blockIdx.x;   // side*8 + b, 0..15
    const int tid = threadIdx.x;
    r[tid] = racc[bid * 256 + tid] * (1.f / 2048.f);
    __syncthreads();
    float s = bfv[tid];
    for (int k = 0; k < 256; ++k)
        s += r[k] * Wf[k * 256 + tid];
    out[bid * 256 + tid] = s;
}

// ---------------------------------------------------------------------------
extern "C" void kernel_launch(void* const* d_in, const int* in_sizes, int n_in,
                              void* d_out, int out_size, void* d_ws, size_t ws_size,
                              hipStream_t stream) {
    // setup_inputs() dict order; float tensors fp32, index tensors int32
    const float* h[2]   = {(const float*)d_in[0],  (const float*)d_in[1]};
    const int* den[2]   = {(const int*)d_in[4],  (const int*)d_in[11]};
    const int* spa[2]   = {(const int*)d_in[5],  (const int*)d_in[12]};
    const int* arc[2]   = {(const int*)d_in[7],  (const int*)d_in[14]};
    const int* wty[2]   = {(const int*)d_in[9],  (const int*)d_in[16]};
    const int* wma[2]   = {(const int*)d_in[10], (const int*)d_in[17]};
    const float* W1[2]  = {(const float*)d_in[18], (const float*)d_in[22]};
    const float* b1[2]  = {(const float*)d_in[19], (const float*)d_in[23]};
    const float* W2[2]  = {(const float*)d_in[20], (const float*)d_in[24]};
    const float* b2[2]  = {(const float*)d_in[21], (const float*)d_in[25]};
    const float* emb    = (const float*)d_in[26];
    const float* Wmsg   = (const float*)d_in[27];
    const float* bmsg   = (const float*)d_in[28];
    const float* Wedge  = (const float*)d_in[29];
    const float* Wself  = (const float*)d_in[31];
    const float* bself  = (const float*)d_in[32];
    const float* Wf     = (const float*)d_in[33];
    const float* bf_    = (const float*)d_in[34];

    char* ws = (char*)d_ws;
    size_t off = 0;
    auto alloc = [&](size_t bytes) -> void* {
        void* pp = ws + off; off += (bytes + 255) & ~(size_t)255; return pp;
    };
    u16*   x1    = (u16*)  alloc(2ull * NNODE * 512 * 2);   // 32 MB, MLP hidden
    u16*   xx    = (u16*)  alloc(2ull * NNODE * 256 * 2);   // 16 MB, x
    u16*   xcat  = (u16*)  alloc(2ull * NNODE * 512 * 2);   // 32 MB, [msg|self]
    u16*   W1T   = (u16*)  alloc(2ull * 512 * 1024 * 2);
    u16*   W2T   = (u16*)  alloc(2ull * 256 * 512 * 2);
    u16*   WcatT = (u16*)  alloc(512 * 256 * 2);            // [WmsgT ; WselfT]
    float* EW    = (float*)alloc(64 * 256 * 4);
    float* bcat  = (float*)alloc(512 * 4);
    float* racc  = (float*)alloc(2 * 8 * 256 * 4);

    // prep: weights transpose+convert to [N,K] bf16 (LDS-tiled, coalesced)
    TP tp;
    tp.src[0] = W1[0]; tp.dst[0] = W1T;              tp.K[0] = 1024; tp.N[0] = 512;
    tp.src[1] = W1[1]; tp.dst[1] = W1T + 512 * 1024; tp.K[1] = 1024; tp.N[1] = 512;
    tp.src[2] = W2[0]; tp.dst[2] = W2T;              tp.K[2] = 512;  tp.N[2] = 256;
    tp.src[3] = W2[1]; tp.dst[3] = W2T + 256 * 512;  tp.K[3] = 512;  tp.N[3] = 256;
    tp.src[4] = Wmsg;  tp.dst[4] = WcatT;            tp.K[4] = 256;  tp.N[4] = 256;
    tp.src[5] = Wself; tp.dst[5] = WcatT + 256*256;  tp.K[5] = 256;  tp.N[5] = 256;
    hipLaunchKernelGGL(transpose_k, dim3(128, 6), dim3(256), 0, stream, tp);
    hipLaunchKernelGGL(ew_k, dim3(64), dim3(256), 0, stream, emb, Wedge, EW);
    hipLaunchKernelGGL(bias_cat_k, dim3(1), dim3(256), 0, stream, bmsg, bself, bcat);
    hipMemsetAsync(racc, 0, 2 * 8 * 256 * 4, stream);

    // GEMM1 (fine-phase, fp32-A-in-LDS): [16384,1024]@[1024,512]+b1, leaky
    GemmP g1 = {};
    g1.A[0] = h[0];  g1.A[1] = h[1];
    g1.B[0] = W1T;   g1.B[1] = W1T + 512 * 1024;
    g1.bias[0] = b1[0]; g1.bias[1] = b1[1];
    g1.out[0] = x1;  g1.out[1] = x1 + (size_t)NNODE * 512;
    hipLaunchKernelGGL((gemmf1_k<1>), dim3(256, 1, 2), dim3(512), 0, stream,
                       g1, NNODE, 512, 1024);

    // GEMM2 (fine-phase): [16384,512]@[512,256] + b2 -> xx (bf16)
    GemmP g2 = {};
    g2.A[0] = x1;  g2.A[1] = x1 + (size_t)NNODE * 512;
    g2.B[0] = W2T; g2.B[1] = W2T + 256 * 512;
    g2.bias[0] = b2[0]; g2.bias[1] = b2[1];
    g2.out[0] = xx; g2.out[1] = xx + (size_t)NNODE * 256;
    hipLaunchKernelGGL((gemmt_k<0>), dim3(128, 1, 2), dim3(512), 0, stream,
                       g2, NNODE, 256, 512);

    // GEMM3 (fine-phase, merged msg|self): [16384,256]@[256,512]+bcat -> xcat
    GemmP g3 = {};
    g3.A[0] = xx;    g3.A[1] = xx + (size_t)NNODE * 256;
    g3.B[0] = WcatT; g3.B[1] = WcatT;
    g3.bias[0] = bcat; g3.bias[1] = bcat;
    g3.out[0] = xcat;  g3.out[1] = xcat + (size_t)NNODE * 512;
    hipLaunchKernelGGL((gemmt_k<0>), dim3(256, 1, 2), dim3(512), 0, stream,
                       g3, NNODE, 512, 256);

    // gather + mask + L2-normalize + per-batch mean accumulation
    EpiP ep;
    ep.xcat[0] = xcat; ep.xcat[1] = xcat + (size_t)NNODE * 512;
    for (int s = 0; s < 2; ++s) {
        ep.den[s] = den[s]; ep.spa[s] = spa[s]; ep.arc[s] = arc[s];
        ep.wty[s] = wty[s]; ep.wma[s] = wma[s];
    }
    ep.EW = EW; ep.racc = racc;
    hipLaunchKernelGGL(epi_k, dim3(1024), dim3(256), 0, stream, ep);

    // final projection -> d_out (fp32, src then tgt, 2*8*256)
    hipLaunchKernelGGL(fin_k, dim3(16), dim3(256), 0, stream,
                       racc, Wf, bf_, (float*)d_out);
}